// Round 1
// baseline (673.780 us; speedup 1.0000x reference)
//
#include <hip/hip_runtime.h>

#define C_S 384
#define C_Z 128
#define N_SEQ 1024

// Kernel 1: per-row projections si[n] = dot(s[n], Wi), sj[n] = dot(s[n], Wj) + b.
// One wave per row n. 4 waves per 256-thread block -> 256 blocks.
__global__ __launch_bounds__(256) void sisj_kernel(const float* __restrict__ s,
                                                   const float* __restrict__ W,
                                                   const float* __restrict__ b,
                                                   float* __restrict__ si,
                                                   float* __restrict__ sj) {
    const int lane = threadIdx.x & 63;
    const int wave = threadIdx.x >> 6;
    const int n = blockIdx.x * 4 + wave;

    const float* srow = s + (size_t)n * C_S;
    const float* Wi = W;          // W[0, 0:384]
    const float* Wj = W + C_S;    // W[0, 384:768]

    float acc_i = 0.f, acc_j = 0.f;
#pragma unroll
    for (int j = 0; j < C_S / 64; ++j) {
        const int idx = lane + 64 * j;
        const float v = srow[idx];
        acc_i += v * Wi[idx];
        acc_j += v * Wj[idx];
    }
#pragma unroll
    for (int mask = 32; mask >= 1; mask >>= 1) {
        acc_i += __shfl_xor(acc_i, mask);
        acc_j += __shfl_xor(acc_j, mask);
    }
    if (lane == 0) {
        si[n] = acc_i;
        sj[n] = acc_j + b[0];
    }
}

// Kernel 2: out[o] = dot(z[o, 0:128], Wz) + si[o>>10] + sj[o&1023].
// Each wave computes 2 consecutive outputs: lanes 0-31 -> output o, lanes 32-63 -> o+1.
// Lane l loads float4 of z at channel 4*(l&31); the wave's 64 x 16B loads cover a
// contiguous 1KB segment (perfect coalescing, one dwordx4 per 16B of z ever read).
__global__ __launch_bounds__(256) void contact_kernel(const float* __restrict__ z,
                                                      const float* __restrict__ W,
                                                      const float* __restrict__ si,
                                                      const float* __restrict__ sj,
                                                      float* __restrict__ out) {
    const int lane = threadIdx.x & 63;
    const int wave = threadIdx.x >> 6;
    const int half = lane >> 5;        // which of the 2 outputs
    const int l = lane & 31;           // position within the 32-lane reduction group
    const long long gw = (long long)blockIdx.x * 4 + wave;   // global wave id
    const long long o = gw * 2 + half;                        // flat output index

    // Wz fragment for this lane's channel slice (same for all waves; L1/L2 resident)
    const float4 wz = *(const float4*)(W + 2 * C_S + 4 * l);

    const float4 z4 = *(const float4*)(z + (o << 7) + 4 * l);

    float p = z4.x * wz.x + z4.y * wz.y + z4.z * wz.z + z4.w * wz.w;

    // reduce across the 32-lane half (xor masks <=16 never cross the half boundary)
#pragma unroll
    for (int mask = 16; mask >= 1; mask >>= 1) {
        p += __shfl_xor(p, mask);
    }

    if (l == 0) {
        const int n = (int)(o >> 10);
        const int m = (int)(o & 1023);
        out[o] = p + si[n] + sj[m];
    }
}

extern "C" void kernel_launch(void* const* d_in, const int* in_sizes, int n_in,
                              void* d_out, int out_size, void* d_ws, size_t ws_size,
                              hipStream_t stream) {
    const float* s = (const float*)d_in[0];   // (1,1024,384)
    const float* z = (const float*)d_in[1];   // (1,1024,1024,128)
    const float* W = (const float*)d_in[2];   // (1,896)
    const float* b = (const float*)d_in[3];   // (1,)
    float* out = (float*)d_out;               // (1,1024,1024,1)

    float* si = (float*)d_ws;                 // 1024 floats
    float* sj = si + N_SEQ;                   // 1024 floats

    // 1024 rows, one wave each, 4 waves/block
    sisj_kernel<<<N_SEQ / 4, 256, 0, stream>>>(s, W, b, si, sj);

    // 1024*1024 outputs, 2 per wave, 4 waves/block -> 131072 blocks
    const int total_outputs = N_SEQ * N_SEQ;
    const int blocks = total_outputs / (2 * 4);
    contact_kernel<<<blocks, 256, 0, stream>>>(z, W, si, sj, out);
}